// Round 1
// 751.800 us; speedup vs baseline: 1.0280x; 1.0280x over previous
//
#include <hip/hip_runtime.h>

// Problem dims
#define B_ 128
#define T_ 1024
#define I_ 256
#define H_ 512
#define V_ 32000

typedef float  float4v __attribute__((ext_vector_type(4)));
typedef short  short8  __attribute__((ext_vector_type(8)));

__device__ __forceinline__ unsigned short f2bf(float f){
  unsigned int u = __float_as_uint(f);
  u += 0x7fffu + ((u >> 16) & 1u);          // round-to-nearest-even
  return (unsigned short)(u >> 16);
}
__device__ __forceinline__ ushort4 f2bf4(float4 v){
  ushort4 u; u.x=f2bf(v.x); u.y=f2bf(v.y); u.z=f2bf(v.z); u.w=f2bf(v.w); return u;
}
__device__ __forceinline__ float fast_tanh(float x){
  float e = __expf(2.f*x);
  return 1.f - __fdividef(2.f, e + 1.f);
}
__device__ __forceinline__ float fast_sig(float x){
  return __fdividef(1.f, 1.f + __expf(-x));
}

// ---------------- Wm f32 -> bf16 ----------------
__global__ void conv_bf16(const float4* __restrict__ src, ushort4* __restrict__ dst, int n4){
  int i = blockIdx.x*256 + threadIdx.x;
  if (i < n4) dst[i] = f2bf4(src[i]);
}

// ---------------- small f32 GEMM with K-split atomics ----------------
// out[b][n] += sum_k A[b][k] * W[n][k]   (M=128 fixed)
// mode 0: A=[x|op|hp] K=1280, W=[Wih|Whh], N=2048
// mode 1: A=hn K=512, W=Wq, N=512
// mode 2: A=[hn|ctx] K=1024, W=Wo, N=512
__device__ __forceinline__ const float* fetch_in(int mode, const float* a0, const float* a1,
                                                 const float* a2, int b, int k){
  if (mode == 0){
    if (k < 256)  return a0 + b*256 + k;
    if (k < 768)  return a1 + b*512 + (k-256);
    return a2 + b*512 + (k-768);
  }
  if (mode == 1) return a0 + b*512 + k;
  if (k < 512)   return a0 + b*512 + k;
  return a1 + b*512 + (k-512);
}
__device__ __forceinline__ const float* fetch_w(int mode, const float* w0, const float* w1,
                                                int n, int k){
  if (mode == 0){
    if (k < 768) return w0 + (size_t)n*768 + k;
    return w1 + (size_t)n*512 + (k-768);
  }
  if (mode == 1) return w0 + (size_t)n*512 + k;
  return w0 + (size_t)n*1024 + k;
}

__global__ void sgemm_acc(int mode,
    const float* __restrict__ a0, const float* __restrict__ a1, const float* __restrict__ a2,
    const float* __restrict__ w0, const float* __restrict__ w1,
    float* __restrict__ out, int N, int kchunk)
{
  __shared__ float inp_s[64*132];   // [k][b], pad 128->132
  __shared__ float w_s[64*40];      // [k][n], pad 32->40
  int tid = threadIdx.x;
  int nt = blockIdx.x, kid = blockIdx.y;
  int bg = tid & 31, ng = tid >> 5;           // compute tile: 4b x 4n
  int sb = tid >> 1, skof = (tid & 1)*32;     // input staging
  int wn = tid & 31, wkg = tid >> 5;          // weight staging
  float acc[4][4] = {};
  int substeps = kchunk >> 6;

  for (int s = 0; s < substeps; ++s){
    int ks = kid*kchunk + s*64;
    __syncthreads();
    { // stage inputs: 128 b x 64 k
      const float* src = fetch_in(mode, a0, a1, a2, sb, ks + skof);
      #pragma unroll
      for (int j8 = 0; j8 < 8; ++j8){
        float4 v = ((const float4*)src)[j8];
        int kk = skof + j8*4;
        inp_s[(kk+0)*132 + sb] = v.x;
        inp_s[(kk+1)*132 + sb] = v.y;
        inp_s[(kk+2)*132 + sb] = v.z;
        inp_s[(kk+3)*132 + sb] = v.w;
      }
      // stage weights: 32 n x 64 k
      int nglob = nt*32 + wn;
      const float* wsrc = fetch_w(mode, w0, w1, nglob, ks + wkg*8);
      float4 v0 = ((const float4*)wsrc)[0];
      float4 v1 = ((const float4*)wsrc)[1];
      int kk = wkg*8;
      w_s[(kk+0)*40 + wn] = v0.x;  w_s[(kk+1)*40 + wn] = v0.y;
      w_s[(kk+2)*40 + wn] = v0.z;  w_s[(kk+3)*40 + wn] = v0.w;
      w_s[(kk+4)*40 + wn] = v1.x;  w_s[(kk+5)*40 + wn] = v1.y;
      w_s[(kk+6)*40 + wn] = v1.z;  w_s[(kk+7)*40 + wn] = v1.w;
    }
    __syncthreads();
    #pragma unroll 4
    for (int k = 0; k < 64; ++k){
      float4v vb = *(const float4v*)&inp_s[k*132 + bg*4];
      float4v vw = *(const float4v*)&w_s[k*40 + ng*4];
      #pragma unroll
      for (int i = 0; i < 4; ++i)
        #pragma unroll
        for (int j = 0; j < 4; ++j)
          acc[i][j] = fmaf(vb[i], vw[j], acc[i][j]);
    }
  }
  #pragma unroll
  for (int i = 0; i < 4; ++i)
    #pragma unroll
    for (int j = 0; j < 4; ++j)
      atomicAdd(&out[(size_t)(bg*4+i)*N + nt*32 + ng*4 + j], acc[i][j]);
}

// ---------------- LSTM activations ----------------
__global__ void lstm_act(const float* __restrict__ gates,
    const float* __restrict__ bih, const float* __restrict__ bhh,
    const float* __restrict__ cp, float* __restrict__ hn_out, float* __restrict__ cn_out)
{
  int i = blockIdx.x*256 + threadIdx.x;   // 65536
  int b = i >> 9, h = i & 511;
  const float* g = gates + (size_t)b*2048;
  float g0 = g[h]      + bih[h]      + bhh[h];
  float g1 = g[512+h]  + bih[512+h]  + bhh[512+h];
  float g2 = g[1024+h] + bih[1024+h] + bhh[1024+h];
  float g3 = g[1536+h] + bih[1536+h] + bhh[1536+h];
  float ig = fast_sig(g0), fg = fast_sig(g1);
  float gg = fast_tanh(g2), og = fast_sig(g3);
  float cv = fg*cp[i] + ig*gg;
  float hv = og*fast_tanh(cv);
  cn_out[i] = cv;
  hn_out[i] = hv;
}

// ---------------- fused attention: k-GEMM + tanh·Wa + online softmax + ctx partial ----------
// grid 1024 = (b=128) x (tc=8), block 512 (8 waves, 2M x 4N wave grid)
// wave tile 64t x 128n (acc 4x8), double-buffered LDS, reg-prefetch staging (T14):
//   - 12 ds_read_b128 per 32 MFMA per wave (was 8 per 16) -> LDS pressure ~2.6x MFMA (was 4.2x)
//   - one barrier per K-step (was two), global loads issued one full iteration ahead
__global__ __launch_bounds__(512, 2) void attn_fused(
    const float* __restrict__ enc, const unsigned short* __restrict__ wmbf,
    const float* __restrict__ q, const float* __restrict__ wa,
    float* __restrict__ scores, float* __restrict__ ml, float* __restrict__ ctxp)
{
  __shared__ unsigned short As[2][128*40];   // enc tile (t x k), bf16, pad 32->40
  __shared__ unsigned short Bs[2][512*40];   // Wm tile (n x k), bf16
  __shared__ float qs[512], was[512], sbuf[128], redbuf[4];

  int tid = threadIdx.x;
  int bidx = blockIdx.x >> 3, tc = blockIdx.x & 7;
  int tbase = tc * 128;
  int w = tid >> 6, lane = tid & 63;
  int wm = w >> 2, wn4 = w & 3;
  int c = lane & 15, q4 = lane >> 4;

  qs[tid]  = q[bidx*512 + tid];
  was[tid] = wa[tid];
  if (tid < 128) sbuf[tid] = 0.f;

  float4v acc[4][8];
  #pragma unroll
  for (int i = 0; i < 4; ++i)
    #pragma unroll
    for (int j = 0; j < 8; ++j) acc[i][j] = (float4v)0.f;

  // A staging: 128 rows x 32 k f32; thread -> row tid>>2, 8 floats at (tid&3)*8
  int arow = tid >> 2, akof = (tid & 3)*8;
  const float* asrc = enc + ((size_t)bidx*1024 + tbase + arow)*512 + akof;
  // B staging: one Wm row chunk (32 bf16 = 64B) per thread
  const unsigned short* bsrc = wmbf + (size_t)tid*512;

  float4 pa0, pa1;
  uint4  pb0, pb1, pb2, pb3;

  // prologue: load step 0 -> regs
  pa0 = *(const float4*)(asrc);
  pa1 = *(const float4*)(asrc + 4);
  { const uint4* bp = (const uint4*)(bsrc);
    pb0 = bp[0]; pb1 = bp[1]; pb2 = bp[2]; pb3 = bp[3]; }
  // write buf 0
  {
    unsigned short* asd = &As[0][arow*40 + akof];
    *(ushort4*)asd       = f2bf4(pa0);
    *(ushort4*)(asd + 4) = f2bf4(pa1);
    uint4* bq = (uint4*)&Bs[0][tid*40];
    bq[0] = pb0; bq[1] = pb1; bq[2] = pb2; bq[3] = pb3;
  }
  // load step 1 -> regs
  pa0 = *(const float4*)(asrc + 32);
  pa1 = *(const float4*)(asrc + 36);
  { const uint4* bp = (const uint4*)(bsrc + 32);
    pb0 = bp[0]; pb1 = bp[1]; pb2 = bp[2]; pb3 = bp[3]; }
  __syncthreads();

  for (int ks = 0; ks < 16; ++ks){
    int cur = ks & 1;
    if (ks < 15){
      // write prefetched (ks+1) regs -> other buffer (safe: last read at ks-1, barrier since)
      unsigned short* asd = &As[cur^1][arow*40 + akof];
      *(ushort4*)asd       = f2bf4(pa0);
      *(ushort4*)(asd + 4) = f2bf4(pa1);
      uint4* bq = (uint4*)&Bs[cur^1][tid*40];
      bq[0] = pb0; bq[1] = pb1; bq[2] = pb2; bq[3] = pb3;
      if (ks < 14){
        // issue (ks+2) global loads; latency hides under this step's MFMA
        int k0 = (ks+2)*32;
        pa0 = *(const float4*)(asrc + k0);
        pa1 = *(const float4*)(asrc + k0 + 4);
        const uint4* bp = (const uint4*)(bsrc + k0);
        pb0 = bp[0]; pb1 = bp[1]; pb2 = bp[2]; pb3 = bp[3];
      }
    }
    short8 af[4];
    #pragma unroll
    for (int mi = 0; mi < 4; ++mi)
      af[mi] = *(const short8*)&As[cur][(wm*64 + mi*16 + c)*40 + q4*8];
    #pragma unroll
    for (int ni = 0; ni < 8; ++ni){
      short8 bf = *(const short8*)&Bs[cur][(wn4*128 + ni*16 + c)*40 + q4*8];
      #pragma unroll
      for (int mi = 0; mi < 4; ++mi)
        acc[mi][ni] = __builtin_amdgcn_mfma_f32_16x16x32_bf16(af[mi], bf, acc[mi][ni], 0, 0, 0);
    }
    __syncthreads();
  }

  // scores: s[t] += sum_n wa[n]*tanh(q[n]+k[t,n]) over this wave's 128 columns
  float qv[8], wv[8];
  #pragma unroll
  for (int ni = 0; ni < 8; ++ni){
    int n = wn4*128 + ni*16 + c;
    qv[ni] = qs[n]; wv[ni] = was[n];
  }
  #pragma unroll
  for (int mi = 0; mi < 4; ++mi){
    #pragma unroll
    for (int r = 0; r < 4; ++r){
      float v = 0.f;
      #pragma unroll
      for (int ni = 0; ni < 8; ++ni)
        v += wv[ni] * fast_tanh(qv[ni] + acc[mi][ni][r]);
      v += __shfl_xor(v, 1); v += __shfl_xor(v, 2);
      v += __shfl_xor(v, 4); v += __shfl_xor(v, 8);
      if (c == 0) atomicAdd(&sbuf[wm*64 + mi*16 + q4*4 + r], v);
    }
  }
  __syncthreads();

  // local softmax over the 128 scores of this chunk (waves 0-1)
  float sval = 0.f;
  if (tid < 128){
    sval = sbuf[tid];
    scores[bidx*1024 + tbase + tid] = sval;
    float m = sval;
    m = fmaxf(m, __shfl_xor(m, 32)); m = fmaxf(m, __shfl_xor(m, 16));
    m = fmaxf(m, __shfl_xor(m, 8));  m = fmaxf(m, __shfl_xor(m, 4));
    m = fmaxf(m, __shfl_xor(m, 2));  m = fmaxf(m, __shfl_xor(m, 1));
    if (lane == 0) redbuf[w] = m;
  }
  __syncthreads();
  float mloc = fmaxf(redbuf[0], redbuf[1]);
  if (tid < 128){
    float p = __expf(sval - mloc);
    sbuf[tid] = p;
    float t = p;
    t += __shfl_xor(t, 32); t += __shfl_xor(t, 16); t += __shfl_xor(t, 8);
    t += __shfl_xor(t, 4);  t += __shfl_xor(t, 2);  t += __shfl_xor(t, 1);
    if (lane == 0) redbuf[2 + w] = t;
  }
  __syncthreads();
  if (tid == 0){
    ml[(bidx*8 + tc)*2 + 0] = mloc;
    ml[(bidx*8 + tc)*2 + 1] = redbuf[2] + redbuf[3];
  }
  // context partial: ctx[n] = sum_t p[t]*enc[b,t,n]  (enc chunk is L2-hot)
  const float* ep = enc + ((size_t)bidx*1024 + tbase)*512 + tid;
  float a = 0.f;
  #pragma unroll 8
  for (int t2 = 0; t2 < 128; ++t2)
    a = fmaf(sbuf[t2], ep[(size_t)t2*512], a);
  ctxp[((size_t)bidx*8 + tc)*512 + tid] = a;
}

// ---------------- softmax combine across 8 chunks + weights output ----------------
__global__ void attn_combine(const float* __restrict__ ml, const float* __restrict__ ctxp,
    const float* __restrict__ scores, float* __restrict__ ctx, float* __restrict__ wfinal)
{
  int b = blockIdx.x, tid = threadIdx.x;
  float M = -1e30f;
  #pragma unroll
  for (int i = 0; i < 8; ++i) M = fmaxf(M, ml[(b*8+i)*2]);
  float L = 0.f, ef[8];
  #pragma unroll
  for (int i = 0; i < 8; ++i){
    ef[i] = __expf(ml[(b*8+i)*2] - M);
    L += ml[(b*8+i)*2+1] * ef[i];
  }
  float invL = __fdividef(1.f, L);
  for (int n = tid; n < 512; n += 256){
    float v = 0.f;
    #pragma unroll
    for (int i = 0; i < 8; ++i) v += ef[i]*ctxp[((size_t)b*8 + i)*512 + n];
    ctx[b*512 + n] = v*invL;
  }
  for (int t = tid; t < 1024; t += 256)
    wfinal[b*1024 + t] = __expf(scores[b*1024 + t] - M)*invL;
}

// ---------------- tanh activation (on) ----------------
__global__ void tanh_act(const float* __restrict__ in, float* __restrict__ out){
  int i = blockIdx.x*256 + threadIdx.x;   // 65536
  out[i] = fast_tanh(in[i]);
}

// ---------------- head GEMM: logits = on @ Wout^T (bf16 MFMA) ----------------
// grid 250, block 256 (4 waves, 2x2), WG tile 128 x 128, K=512
__global__ void head_gemm(const float* __restrict__ onv, const float* __restrict__ wout,
                          float* __restrict__ outp)
{
  __shared__ unsigned short As[128*40];
  __shared__ unsigned short Bs[128*40];
  int tid = threadIdx.x;
  int n0 = blockIdx.x * 128;
  int w = tid >> 6, lane = tid & 63;
  int wm = w >> 1, wn = w & 1;
  int c = lane & 15, q4 = lane >> 4;
  float4v acc[4][4];
  #pragma unroll
  for (int i = 0; i < 4; ++i)
    #pragma unroll
    for (int j = 0; j < 4; ++j) acc[i][j] = (float4v)0.f;

  int row = tid >> 1, kof = (tid & 1)*16;
  const float* sa = onv + (size_t)row*512 + kof;
  const float* sb = wout + (size_t)(n0 + row)*512 + kof;

  for (int ks = 0; ks < 16; ++ks){
    int k0 = ks*32;
    __syncthreads();
    #pragma unroll
    for (int j = 0; j < 4; ++j){
      float4 va = *(const float4*)(sa + k0 + j*4);
      *(ushort4*)&As[row*40 + kof + j*4] = f2bf4(va);
      float4 vb = *(const float4*)(sb + k0 + j*4);
      *(ushort4*)&Bs[row*40 + kof + j*4] = f2bf4(vb);
    }
    __syncthreads();
    short8 af[4];
    #pragma unroll
    for (int mi = 0; mi < 4; ++mi)
      af[mi] = *(const short8*)&As[(wm*64 + mi*16 + c)*40 + q4*8];
    #pragma unroll
    for (int ni = 0; ni < 4; ++ni){
      short8 bf = *(const short8*)&Bs[(wn*64 + ni*16 + c)*40 + q4*8];
      #pragma unroll
      for (int mi = 0; mi < 4; ++mi)
        acc[mi][ni] = __builtin_amdgcn_mfma_f32_16x16x32_bf16(af[mi], bf, acc[mi][ni], 0, 0, 0);
    }
  }
  #pragma unroll
  for (int mi = 0; mi < 4; ++mi)
    #pragma unroll
    for (int ni = 0; ni < 4; ++ni)
      #pragma unroll
      for (int r = 0; r < 4; ++r){
        int m = wm*64 + mi*16 + q4*4 + r;
        int n = n0 + wn*64 + ni*16 + c;
        outp[(size_t)m*32000 + n] = acc[mi][ni][r];
      }
}

// ---------------- per-row logsumexp + in-place subtract ----------------
__global__ void lse_rows(const float* __restrict__ outp, float* __restrict__ lse){
  __shared__ float rm[4], rs[4];
  int b = blockIdx.x, tid = threadIdx.x;
  int w = tid >> 6, lane = tid & 63;
  const float* row = outp + (size_t)b*32000;
  float m = -1e30f, s = 0.f;
  for (int v = tid; v < 32000; v += 256){
    float x = row[v];
    if (x > m){ s = s*__expf(m - x) + 1.f; m = x; }
    else s += __expf(x - m);
  }
  for (int off = 32; off; off >>= 1){
    float mo = __shfl_xor(m, off), so = __shfl_xor(s, off);
    float M2 = fmaxf(m, mo);
    s = s*__expf(m - M2) + so*__expf(mo - M2);
    m = M2;
  }
  if (lane == 0){ rm[w] = m; rs[w] = s; }
  __syncthreads();
  if (tid == 0){
    float M2 = fmaxf(fmaxf(rm[0], rm[1]), fmaxf(rm[2], rm[3]));
    float S = rs[0]*__expf(rm[0]-M2) + rs[1]*__expf(rm[1]-M2)
            + rs[2]*__expf(rm[2]-M2) + rs[3]*__expf(rm[3]-M2);
    lse[b] = M2 + __logf(S);
  }
}

__global__ void sub_lse(float4* outp4, const float* __restrict__ lse){
  int i = blockIdx.x*256 + threadIdx.x;   // 1,024,000 float4 exactly
  int b = i / 8000;
  float l = lse[b];
  float4 v = outp4[i];
  v.x -= l; v.y -= l; v.z -= l; v.w -= l;
  outp4[i] = v;
}

extern "C" void kernel_launch(void* const* d_in, const int* in_sizes, int n_in,
                              void* d_out, int out_size, void* d_ws, size_t ws_size,
                              hipStream_t stream)
{
  (void)in_sizes; (void)n_in; (void)out_size; (void)ws_size;
  const float* x    = (const float*)d_in[0];
  const float* hp   = (const float*)d_in[1];
  const float* cp   = (const float*)d_in[2];
  const float* op   = (const float*)d_in[3];
  const float* enc  = (const float*)d_in[4];
  const float* Wih  = (const float*)d_in[5];
  const float* Whh  = (const float*)d_in[6];
  const float* bih  = (const float*)d_in[7];
  const float* bhh  = (const float*)d_in[8];
  const float* Wq   = (const float*)d_in[9];
  const float* Wm   = (const float*)d_in[10];
  const float* Wa   = (const float*)d_in[11];
  const float* Wo   = (const float*)d_in[12];
  const float* Wout = (const float*)d_in[13];
  float* out = (float*)d_out;

  float* ws = (float*)d_ws;
  float* gates   = ws + 0;                               // 262144
  float* qbuf    = ws + 262144;                          // 65536
  unsigned short* wmbf = (unsigned short*)(ws + 327680); // 262144 bf16
  float* scoresb = ws + 458752;                          // 131072
  float* mlb     = ws + 589824;                          // 2048
  float* ctxpb   = ws + 591872;                          // 524288
  float* ctxb    = ws + 1116160;                         // 65536
  float* oaccb   = ws + 1181696;                         // 65536
  float* lseb    = ws + 1247232;                         // 128

  float* out_logits = out;                 // 4,096,000
  float* out_hn = out + 4096000;           // 65,536
  float* out_cn = out + 4161536;           // 65,536
  float* out_on = out + 4227072;           // 65,536
  float* out_w  = out + 4292608;           // 131,072

  hipMemsetAsync(gates, 0, (size_t)(262144 + 65536)*sizeof(float), stream); // gates + q
  hipMemsetAsync(oaccb, 0, (size_t)65536*sizeof(float), stream);

  conv_bf16<<<256, 256, 0, stream>>>((const float4*)Wm, (ushort4*)wmbf, 65536);
  sgemm_acc<<<dim3(64, 4), 256, 0, stream>>>(0, x, op, hp, Wih, Whh, gates, 2048, 320);
  lstm_act<<<256, 256, 0, stream>>>(gates, bih, bhh, cp, out_hn, out_cn);
  sgemm_acc<<<dim3(16, 8), 256, 0, stream>>>(1, out_hn, nullptr, nullptr, Wq, nullptr, qbuf, 512, 64);
  attn_fused<<<1024, 512, 0, stream>>>(enc, wmbf, qbuf, Wa, scoresb, mlb, ctxpb);
  attn_combine<<<128, 256, 0, stream>>>(mlb, ctxpb, scoresb, ctxb, out_w);
  sgemm_acc<<<dim3(16, 8), 256, 0, stream>>>(2, out_hn, ctxb, nullptr, Wo, nullptr, oaccb, 512, 128);
  tanh_act<<<256, 256, 0, stream>>>(oaccb, out_on);
  head_gemm<<<250, 256, 0, stream>>>(out_on, Wout, out_logits);
  lse_rows<<<128, 256, 0, stream>>>(out_logits, lseb);
  sub_lse<<<4000, 256, 0, stream>>>((float4*)out_logits, lseb);
}